// Round 2
// baseline (2360.426 us; speedup 1.0000x reference)
//
#include <hip/hip_runtime.h>
#include <cstdint>
#include <cstddef>

typedef _Float16 f16;
typedef _Float16 f16x4 __attribute__((ext_vector_type(4)));
typedef _Float16 f16x8 __attribute__((ext_vector_type(8)));
typedef float f32x4 __attribute__((ext_vector_type(4)));

// ---------- sizes ----------
#define SEQ 1024
#define BATCH 128
#define INDIM 256
#define HDIM 512
#define MROWS (SEQ * BATCH)          // 131072
#define NCOLS (3 * HDIM)             // 1536
#define BHDIM (BATCH * HDIM)         // 65536
#define TCHUNK 128                   // timesteps per chunk
#define CHROWS (TCHUNK * BATCH)      // 16384 rows per GEMM chunk

// workspace layout (bytes); total 372,512,768 < proven-available (>=538MB)
#define P32_OFF   0ull                         // [16384][1536] f32 = 100,663,296
#define Y0_OFF    100663296ull                 // [131072][512] f32 = 268,435,456
#define WHI_OFF   369098752ull                 // [1536][512] f16   = 1,572,864
#define WLO_OFF   370671616ull                 // [1536][512] f16   = 1,572,864
#define BIAS_OFF  372244480ull                 // [1536] f32        = 6,144
#define HST_OFF   372250624ull                 // [65536] f32       = 262,144
#define WS_NEEDED 372512768ull

__device__ __forceinline__ float fast_tanh(float x) {
  return 1.0f - 2.0f / (__expf(2.0f * x) + 1.0f);
}
__device__ __forceinline__ float fast_sigmoid(float x) {
  return 1.0f / (1.0f + __expf(-x));
}

// ---------- f32 -> (hi f16, lo' f16 = (v-hi)*2048) split ----------
__global__ __launch_bounds__(256) void split_kernel(const float* __restrict__ in,
                                                    f16* __restrict__ hi,
                                                    f16* __restrict__ lo, int n4) {
  int stride = gridDim.x * blockDim.x;
  for (int i = blockIdx.x * blockDim.x + threadIdx.x; i < n4; i += stride) {
    float4 v = reinterpret_cast<const float4*>(in)[i];
    f16x4 h4 = {(f16)v.x, (f16)v.y, (f16)v.z, (f16)v.w};
    f16x4 l4 = {(f16)((v.x - (float)h4[0]) * 2048.0f),
                (f16)((v.y - (float)h4[1]) * 2048.0f),
                (f16)((v.z - (float)h4[2]) * 2048.0f),
                (f16)((v.w - (float)h4[3]) * 2048.0f)};
    reinterpret_cast<f16x4*>(hi)[i] = h4;
    reinterpret_cast<f16x4*>(lo)[i] = l4;
  }
}

// ---------- GEMM: P[CHROWS,1536](f32) = A[CHROWS,K](f32) . W[1536,K]^T + bias ----------
// A is split to (hi, lo*2048) f16 during staging. acc = Ahi.Bhi ; accc = Ahi.Blo' + Alo'.Bhi
// P = acc + accc/2048 + bias  -> ~f32-accurate product terms.
__global__ __launch_bounds__(256, 1) void gemm_split_kernel(const float* __restrict__ A,
                                                            const f16* __restrict__ Whi,
                                                            const f16* __restrict__ Wlo,
                                                            const float* __restrict__ bias,
                                                            float* __restrict__ P, int K) {
  constexpr int BK = 32;
  constexpr int LDSS = BK + 8;  // 40 f16 row stride (80 B, 16B-aligned)
  __shared__ f16 Ah[128 * LDSS];
  __shared__ f16 Al[128 * LDSS];
  __shared__ f16 Bh[128 * LDSS];
  __shared__ f16 Bl[128 * LDSS];

  const int tid = threadIdx.x;
  const int lane = tid & 63;
  const int wid = tid >> 6;
  const int wm = (wid >> 1) * 64;
  const int wn = (wid & 1) * 64;
  const long m0 = (long)blockIdx.x * 128;
  const int n0 = blockIdx.y * 128;

  const int fr = lane & 15;
  const int fk = (lane >> 4) * 8;

  f32x4 acc[4][4] = {};
  f32x4 accc[4][4] = {};

  for (int k0 = 0; k0 < K; k0 += BK) {
    // stage A (f32 -> split f16): 128 rows x 32 cols = 1024 float4, 4 rounds
#pragma unroll
    for (int r = 0; r < 4; ++r) {
      int idx = r * 256 + tid;
      int row = idx >> 3;
      int c4 = (idx & 7) << 2;
      float4 v = *reinterpret_cast<const float4*>(A + (m0 + row) * K + k0 + c4);
      f16x4 h4 = {(f16)v.x, (f16)v.y, (f16)v.z, (f16)v.w};
      f16x4 l4 = {(f16)((v.x - (float)h4[0]) * 2048.0f),
                  (f16)((v.y - (float)h4[1]) * 2048.0f),
                  (f16)((v.z - (float)h4[2]) * 2048.0f),
                  (f16)((v.w - (float)h4[3]) * 2048.0f)};
      *reinterpret_cast<f16x4*>(&Ah[row * LDSS + c4]) = h4;
      *reinterpret_cast<f16x4*>(&Al[row * LDSS + c4]) = l4;
    }
    // stage B (pre-split f16): 128 rows x 32 cols = 512 f16x8, 2 rounds per matrix
#pragma unroll
    for (int r = 0; r < 2; ++r) {
      int idx = r * 256 + tid;
      int row = idx >> 2;
      int c8 = (idx & 3) << 3;
      *reinterpret_cast<f16x8*>(&Bh[row * LDSS + c8]) =
          *reinterpret_cast<const f16x8*>(Whi + (long)(n0 + row) * K + k0 + c8);
      *reinterpret_cast<f16x8*>(&Bl[row * LDSS + c8]) =
          *reinterpret_cast<const f16x8*>(Wlo + (long)(n0 + row) * K + k0 + c8);
    }
    __syncthreads();

    f16x8 ah[4], al[4], bh4[4], bl4[4];
#pragma unroll
    for (int i = 0; i < 4; ++i) {
      ah[i] = *reinterpret_cast<const f16x8*>(&Ah[(wm + i * 16 + fr) * LDSS + fk]);
      al[i] = *reinterpret_cast<const f16x8*>(&Al[(wm + i * 16 + fr) * LDSS + fk]);
      bh4[i] = *reinterpret_cast<const f16x8*>(&Bh[(wn + i * 16 + fr) * LDSS + fk]);
      bl4[i] = *reinterpret_cast<const f16x8*>(&Bl[(wn + i * 16 + fr) * LDSS + fk]);
    }

#pragma unroll
    for (int i = 0; i < 4; ++i)
#pragma unroll
      for (int j = 0; j < 4; ++j) {
        acc[i][j] = __builtin_amdgcn_mfma_f32_16x16x32_f16(ah[i], bh4[j], acc[i][j], 0, 0, 0);
        accc[i][j] = __builtin_amdgcn_mfma_f32_16x16x32_f16(ah[i], bl4[j], accc[i][j], 0, 0, 0);
        accc[i][j] = __builtin_amdgcn_mfma_f32_16x16x32_f16(al[i], bh4[j], accc[i][j], 0, 0, 0);
      }
    __syncthreads();
  }

  // epilogue: col = lane&15, row = (lane>>4)*4 + reg
  const int crow = (lane >> 4) * 4;
  const int ccol = lane & 15;
#pragma unroll
  for (int j = 0; j < 4; ++j) {
    int gc = n0 + wn + j * 16 + ccol;
    float bv = bias[gc];
#pragma unroll
    for (int i = 0; i < 4; ++i) {
      long gr = m0 + wm + i * 16 + crow;
#pragma unroll
      for (int r = 0; r < 4; ++r) {
        P[(gr + r) * NCOLS + gc] = acc[i][j][r] + accc[i][j][r] * (1.0f / 2048.0f) + bv;
      }
    }
  }
}

// ---------- BRC scan over one t-chunk: one thread per (b,h) chain ----------
__global__ __launch_bounds__(256) void scan_kernel(const float* __restrict__ P,
                                                   const float* __restrict__ hinit,
                                                   float* __restrict__ hstate,
                                                   int first,
                                                   const float* __restrict__ wc,
                                                   const float* __restrict__ wa,
                                                   float* __restrict__ Y,   // [SEQ][B][H] f32
                                                   float* __restrict__ HN,  // null unless last
                                                   int tc) {
  const int j = blockIdx.x * 256 + threadIdx.x;  // 0..65535
  const int hh = j & (HDIM - 1);
  float h = first ? hinit[j] : hstate[j];
  const float wcv = wc[hh];
  const float wav = wa[hh];
  const float* p = P + (long)(j >> 9) * NCOLS + hh;
  float* y = Y + ((long)tc * TCHUNK) * BHDIM + j;
#pragma unroll 4
  for (int t = 0; t < TCHUNK; ++t) {
    float pc = p[0];
    float pa = p[HDIM];
    float ph = p[2 * HDIM];
    float c = fast_sigmoid(fmaf(wcv, h, pc));
    float a = 1.0f + fast_tanh(fmaf(wav, h, pa));
    h = c * h + (1.0f - c) * fast_tanh(fmaf(a, h, ph));
    *y = h;
    y += BHDIM;
    p += BATCH * NCOLS;
  }
  hstate[j] = h;
  if (HN) HN[j] = h;
}

extern "C" void kernel_launch(void* const* d_in, const int* in_sizes, int n_in,
                              void* d_out, int out_size, void* d_ws, size_t ws_size,
                              hipStream_t stream) {
  const float* x   = (const float*)d_in[0];
  const float* h0  = (const float*)d_in[1];
  const float* Uc0 = (const float*)d_in[2];
  const float* wc0 = (const float*)d_in[3];
  const float* bc0 = (const float*)d_in[4];
  const float* Ua0 = (const float*)d_in[5];
  const float* wa0 = (const float*)d_in[6];
  const float* ba0 = (const float*)d_in[7];
  const float* Uh0 = (const float*)d_in[8];
  const float* bh0 = (const float*)d_in[9];
  const float* Uc1 = (const float*)d_in[10];
  const float* wc1 = (const float*)d_in[11];
  const float* bc1 = (const float*)d_in[12];
  const float* Ua1 = (const float*)d_in[13];
  const float* wa1 = (const float*)d_in[14];
  const float* ba1 = (const float*)d_in[15];
  const float* Uh1 = (const float*)d_in[16];
  const float* bh1 = (const float*)d_in[17];

  if (ws_size < WS_NEEDED) return;

  char* ws = (char*)d_ws;
  float* p32  = (float*)(ws + P32_OFF);
  float* y0   = (float*)(ws + Y0_OFF);
  f16* whi    = (f16*)(ws + WHI_OFF);
  f16* wlo    = (f16*)(ws + WLO_OFF);
  float* bias = (float*)(ws + BIAS_OFF);
  float* hst  = (float*)(ws + HST_OFF);

  float* y1  = (float*)d_out;
  float* hn0 = y1 + (long)SEQ * BHDIM;
  float* hn1 = hn0 + BHDIM;

  const int NCH = SEQ / TCHUNK;  // 8

  // ---- layer 0 weights/bias (K=256) ----
  hipLaunchKernelGGL(split_kernel, dim3(128), dim3(256), 0, stream, Uc0,
                     whi + 0 * HDIM * INDIM, wlo + 0 * HDIM * INDIM, HDIM * INDIM / 4);
  hipLaunchKernelGGL(split_kernel, dim3(128), dim3(256), 0, stream, Ua0,
                     whi + 1 * HDIM * INDIM, wlo + 1 * HDIM * INDIM, HDIM * INDIM / 4);
  hipLaunchKernelGGL(split_kernel, dim3(128), dim3(256), 0, stream, Uh0,
                     whi + 2 * HDIM * INDIM, wlo + 2 * HDIM * INDIM, HDIM * INDIM / 4);
  hipMemcpyAsync(bias + 0 * HDIM, bc0, HDIM * sizeof(float), hipMemcpyDeviceToDevice, stream);
  hipMemcpyAsync(bias + 1 * HDIM, ba0, HDIM * sizeof(float), hipMemcpyDeviceToDevice, stream);
  hipMemcpyAsync(bias + 2 * HDIM, bh0, HDIM * sizeof(float), hipMemcpyDeviceToDevice, stream);

  // ---- layer 0: chunked GEMM + scan ----
  for (int tc = 0; tc < NCH; ++tc) {
    hipLaunchKernelGGL(gemm_split_kernel, dim3(CHROWS / 128, NCOLS / 128), dim3(256), 0, stream,
                       x + (long)tc * CHROWS * INDIM, whi, wlo, bias, p32, INDIM);
    hipLaunchKernelGGL(scan_kernel, dim3(BHDIM / 256), dim3(256), 0, stream,
                       p32, h0, hst, (tc == 0) ? 1 : 0, wc0, wa0, y0,
                       (tc == NCH - 1) ? hn0 : (float*)nullptr, tc);
  }

  // ---- layer 1 weights/bias (K=512) ----
  hipLaunchKernelGGL(split_kernel, dim3(256), dim3(256), 0, stream, Uc1,
                     whi + 0 * HDIM * HDIM, wlo + 0 * HDIM * HDIM, HDIM * HDIM / 4);
  hipLaunchKernelGGL(split_kernel, dim3(256), dim3(256), 0, stream, Ua1,
                     whi + 1 * HDIM * HDIM, wlo + 1 * HDIM * HDIM, HDIM * HDIM / 4);
  hipLaunchKernelGGL(split_kernel, dim3(256), dim3(256), 0, stream, Uh1,
                     whi + 2 * HDIM * HDIM, wlo + 2 * HDIM * HDIM, HDIM * HDIM / 4);
  hipMemcpyAsync(bias + 0 * HDIM, bc1, HDIM * sizeof(float), hipMemcpyDeviceToDevice, stream);
  hipMemcpyAsync(bias + 1 * HDIM, ba1, HDIM * sizeof(float), hipMemcpyDeviceToDevice, stream);
  hipMemcpyAsync(bias + 2 * HDIM, bh1, HDIM * sizeof(float), hipMemcpyDeviceToDevice, stream);

  // ---- layer 1: chunked GEMM + scan ----
  for (int tc = 0; tc < NCH; ++tc) {
    hipLaunchKernelGGL(gemm_split_kernel, dim3(CHROWS / 128, NCOLS / 128), dim3(256), 0, stream,
                       y0 + (long)tc * CHROWS * HDIM, whi, wlo, bias, p32, HDIM);
    hipLaunchKernelGGL(scan_kernel, dim3(BHDIM / 256), dim3(256), 0, stream,
                       p32, h0 + BHDIM, hst, (tc == 0) ? 1 : 0, wc1, wa1, y1,
                       (tc == NCH - 1) ? hn1 : (float*)nullptr, tc);
  }
}

// Round 5
// 2299.714 us; speedup vs baseline: 1.0264x; 1.0264x over previous
//
#include <hip/hip_runtime.h>
#include <cstdint>
#include <cstddef>

typedef _Float16 f16;
typedef _Float16 f16x4 __attribute__((ext_vector_type(4)));
typedef _Float16 f16x8 __attribute__((ext_vector_type(8)));
typedef float f32x4 __attribute__((ext_vector_type(4)));

#define AS1 __attribute__((address_space(1)))
#define AS3 __attribute__((address_space(3)))

// ---------- sizes ----------
#define SEQ 1024
#define BATCH 128
#define INDIM 256
#define HDIM 512
#define MROWS (SEQ * BATCH)          // 131072
#define NCOLS (3 * HDIM)             // 1536
#define BHDIM (BATCH * HDIM)         // 65536
#define TCHUNK 128
#define CHROWS (TCHUNK * BATCH)      // 16384

// workspace layout (bytes); total 506,730,496
#define P32_OFF   0ull                         // [16384][1536] f32 = 100,663,296
#define XHI_OFF   100663296ull                 // [131072][256] f16 = 67,108,864
#define XLO_OFF   167772160ull                 // [131072][256] f16 = 67,108,864
#define Y0HI_OFF  234881024ull                 // [131072][512] f16 = 134,217,728
#define Y0LO_OFF  369098752ull                 // [131072][512] f16 = 134,217,728
#define WHI_OFF   503316480ull                 // [1536][512] f16   = 1,572,864
#define WLO_OFF   504889344ull                 // [1536][512] f16   = 1,572,864
#define BIAS_OFF  506462208ull                 // [1536] f32
#define HST_OFF   506468352ull                 // [65536] f32
#define WS_NEEDED 506730496ull

__device__ __forceinline__ float fast_tanh(float x) {
  return 1.0f - 2.0f / (__expf(2.0f * x) + 1.0f);
}
__device__ __forceinline__ float fast_sigmoid(float x) {
  return 1.0f / (1.0f + __expf(-x));
}

__device__ __forceinline__ void gld16(const void* g, void* l) {
  __builtin_amdgcn_global_load_lds((const AS1 void*)g, (AS3 void*)l, 16, 0, 0);
}

// ---------- f32 -> (hi f16, lo' f16 = (v-hi)*2048) split ----------
__global__ __launch_bounds__(256) void split_kernel(const float* __restrict__ in,
                                                    f16* __restrict__ hi,
                                                    f16* __restrict__ lo, int n4) {
  int stride = gridDim.x * blockDim.x;
  for (int i = blockIdx.x * blockDim.x + threadIdx.x; i < n4; i += stride) {
    float4 v = reinterpret_cast<const float4*>(in)[i];
    f16x4 h4 = {(f16)v.x, (f16)v.y, (f16)v.z, (f16)v.w};
    f16x4 l4 = {(f16)((v.x - (float)h4[0]) * 2048.0f),
                (f16)((v.y - (float)h4[1]) * 2048.0f),
                (f16)((v.z - (float)h4[2]) * 2048.0f),
                (f16)((v.w - (float)h4[3]) * 2048.0f)};
    reinterpret_cast<f16x4*>(hi)[i] = h4;
    reinterpret_cast<f16x4*>(lo)[i] = l4;
  }
}

// ---------- GEMM: P[CHROWS,1536](f32) = (Ahi+Alo/2048).(Whi+Wlo/2048)^T + bias ----------
// m97 structure: global_load_lds dwordx4 staging into linear [128][32] f16 LDS x4,
// 2-barrier K-loop, 4 waves (2x2), 4x4 MFMA 16x16x32 frags/wave, 3 MFMA per frag pair.
// Verified (r3/r4 identical-absmax evidence): staging path produces identical results
// to the proven ds_write path.
__global__ __launch_bounds__(256, 2) void gemm_split_kernel(
    const f16* __restrict__ Ahi, const f16* __restrict__ Alo,
    const f16* __restrict__ Whi, const f16* __restrict__ Wlo,
    const float* __restrict__ bias, float* __restrict__ P, int K) {
  constexpr int BK = 32;
  __shared__ f16 sAh[128 * BK];
  __shared__ f16 sAl[128 * BK];
  __shared__ f16 sBh[128 * BK];
  __shared__ f16 sBl[128 * BK];

  const int tid = threadIdx.x;
  const int lane = tid & 63;
  const int w = tid >> 6;
  const int wm = (w >> 1) * 64;
  const int wn = (w & 1) * 64;

  // XCD-aware bijective swizzle (gridDim.x = 1536, %8 == 0), n-block fastest
  const int per = gridDim.x >> 3;
  const int logical = (blockIdx.x & 7) * per + (blockIdx.x >> 3);
  const int nb = logical % (NCOLS / 128);
  const int mb = logical / (NCOLS / 128);
  const long m0 = (long)mb * 128;
  const int n0 = nb * 128;

  const int fr = lane & 15;
  const int fk = (lane >> 4) * 8;

  // staging: wave w stages bytes [w*2048, w*2048+2048) of each 8KB tile in 2 rounds of
  // 1KB (64 lanes x 16B). LDS dest is wave-uniform base; HW adds lane*16. Global source
  // is per-lane: row = off>>6 (64B/row), colb = off&63 — matches LDS landing slot.
  const int off0 = w * 2048 + lane * 16;
  const int off1 = off0 + 1024;
  const int row0 = off0 >> 6, colb0 = off0 & 63;
  const int row1 = off1 >> 6, colb1 = off1 & 63;
  const long aoff0 = ((m0 + row0) * (long)K) * 2 + colb0;
  const long aoff1 = ((m0 + row1) * (long)K) * 2 + colb1;
  const long boff0 = ((n0 + row0) * (long)K) * 2 + colb0;
  const long boff1 = ((n0 + row1) * (long)K) * 2 + colb1;
  char* ldsA0h = (char*)sAh + w * 2048;       char* ldsA1h = ldsA0h + 1024;
  char* ldsA0l = (char*)sAl + w * 2048;       char* ldsA1l = ldsA0l + 1024;
  char* ldsB0h = (char*)sBh + w * 2048;       char* ldsB1h = ldsB0h + 1024;
  char* ldsB0l = (char*)sBl + w * 2048;       char* ldsB1l = ldsB0l + 1024;

  f32x4 acc[4][4] = {};
  f32x4 accc[4][4] = {};

  for (int k0 = 0; k0 < K; k0 += BK) {
    const long kb = (long)k0 * 2;
    gld16((const char*)Ahi + aoff0 + kb, ldsA0h);
    gld16((const char*)Ahi + aoff1 + kb, ldsA1h);
    gld16((const char*)Alo + aoff0 + kb, ldsA0l);
    gld16((const char*)Alo + aoff1 + kb, ldsA1l);
    gld16((const char*)Whi + boff0 + kb, ldsB0h);
    gld16((const char*)Whi + boff1 + kb, ldsB1h);
    gld16((const char*)Wlo + boff0 + kb, ldsB0l);
    gld16((const char*)Wlo + boff1 + kb, ldsB1l);
    __syncthreads();   // drains vmcnt -> LDS tiles ready

    f16x8 ah[4], al[4], bh[4], bl[4];
#pragma unroll
    for (int i = 0; i < 4; ++i) {
      ah[i] = *reinterpret_cast<const f16x8*>(&sAh[(wm + i * 16 + fr) * BK + fk]);
      al[i] = *reinterpret_cast<const f16x8*>(&sAl[(wm + i * 16 + fr) * BK + fk]);
      bh[i] = *reinterpret_cast<const f16x8*>(&sBh[(wn + i * 16 + fr) * BK + fk]);
      bl[i] = *reinterpret_cast<const f16x8*>(&sBl[(wn + i * 16 + fr) * BK + fk]);
    }

#pragma unroll
    for (int i = 0; i < 4; ++i)
#pragma unroll
      for (int j = 0; j < 4; ++j) {
        acc[i][j]  = __builtin_amdgcn_mfma_f32_16x16x32_f16(ah[i], bh[j], acc[i][j], 0, 0, 0);
        accc[i][j] = __builtin_amdgcn_mfma_f32_16x16x32_f16(ah[i], bl[j], accc[i][j], 0, 0, 0);
        accc[i][j] = __builtin_amdgcn_mfma_f32_16x16x32_f16(al[i], bh[j], accc[i][j], 0, 0, 0);
      }
    __syncthreads();   // protect LDS before next stage
  }

  // epilogue: C/D layout col = lane&15, row = (lane>>4)*4 + reg
  const int crow = (lane >> 4) * 4;
  const int ccol = lane & 15;
#pragma unroll
  for (int j = 0; j < 4; ++j) {
    int gc = n0 + wn + j * 16 + ccol;
    float bv = bias[gc];
#pragma unroll
    for (int i = 0; i < 4; ++i) {
      long gr = m0 + wm + i * 16 + crow;
#pragma unroll
      for (int r = 0; r < 4; ++r) {
        P[(gr + r) * NCOLS + gc] = acc[i][j][r] + accc[i][j][r] * (1.0f / 2048.0f) + bv;
      }
    }
  }
}

// ---------- BRC scan over one t-chunk: one thread per (b,h) chain ----------
// ALL output pointers are pre-offset by the caller to this chunk's base.
__global__ __launch_bounds__(256) void scan_kernel(
    const float* __restrict__ P, const float* __restrict__ hinit,
    float* __restrict__ hstate, int first,
    const float* __restrict__ wc, const float* __restrict__ wa,
    f16* __restrict__ Yhi, f16* __restrict__ Ylo,   // layer-0 split outputs (or null)
    float* __restrict__ Yf,                          // layer-1 f32 output (or null)
    float* __restrict__ HN) {
  const int j = blockIdx.x * 256 + threadIdx.x;  // 0..65535
  const int hh = j & (HDIM - 1);
  float h = first ? hinit[j] : hstate[j];
  const float wcv = wc[hh];
  const float wav = wa[hh];
  const float* p = P + (long)(j >> 9) * NCOLS + hh;
  long yo = j;
#pragma unroll 4
  for (int t = 0; t < TCHUNK; ++t) {
    float pc = p[0];
    float pa = p[HDIM];
    float ph = p[2 * HDIM];
    float c = fast_sigmoid(fmaf(wcv, h, pc));
    float a = 1.0f + fast_tanh(fmaf(wav, h, pa));
    h = c * h + (1.0f - c) * fast_tanh(fmaf(a, h, ph));
    if (Yhi) {
      f16 hv = (f16)h;
      Yhi[yo] = hv;
      Ylo[yo] = (f16)((h - (float)hv) * 2048.0f);
    }
    if (Yf) Yf[yo] = h;
    yo += BHDIM;
    p += BATCH * NCOLS;
  }
  hstate[j] = h;
  if (HN) HN[j] = h;
}

extern "C" void kernel_launch(void* const* d_in, const int* in_sizes, int n_in,
                              void* d_out, int out_size, void* d_ws, size_t ws_size,
                              hipStream_t stream) {
  const float* x   = (const float*)d_in[0];
  const float* h0  = (const float*)d_in[1];
  const float* Uc0 = (const float*)d_in[2];
  const float* wc0 = (const float*)d_in[3];
  const float* bc0 = (const float*)d_in[4];
  const float* Ua0 = (const float*)d_in[5];
  const float* wa0 = (const float*)d_in[6];
  const float* ba0 = (const float*)d_in[7];
  const float* Uh0 = (const float*)d_in[8];
  const float* bh0 = (const float*)d_in[9];
  const float* Uc1 = (const float*)d_in[10];
  const float* wc1 = (const float*)d_in[11];
  const float* bc1 = (const float*)d_in[12];
  const float* Ua1 = (const float*)d_in[13];
  const float* wa1 = (const float*)d_in[14];
  const float* ba1 = (const float*)d_in[15];
  const float* Uh1 = (const float*)d_in[16];
  const float* bh1 = (const float*)d_in[17];

  if (ws_size < WS_NEEDED) return;

  char* ws = (char*)d_ws;
  float* p32  = (float*)(ws + P32_OFF);
  f16* xhi    = (f16*)(ws + XHI_OFF);
  f16* xlo    = (f16*)(ws + XLO_OFF);
  f16* y0hi   = (f16*)(ws + Y0HI_OFF);
  f16* y0lo   = (f16*)(ws + Y0LO_OFF);
  f16* whi    = (f16*)(ws + WHI_OFF);
  f16* wlo    = (f16*)(ws + WLO_OFF);
  float* bias = (float*)(ws + BIAS_OFF);
  float* hst  = (float*)(ws + HST_OFF);

  float* y1  = (float*)d_out;
  float* hn0 = y1 + (long)SEQ * BHDIM;
  float* hn1 = hn0 + BHDIM;

  const int NCH = SEQ / TCHUNK;  // 8
  const dim3 gemm_grid(CHROWS / 128 * (NCOLS / 128));  // 1536, %8==0

  // ---- pre-split x ----
  hipLaunchKernelGGL(split_kernel, dim3(2048), dim3(256), 0, stream, x, xhi, xlo,
                     MROWS * INDIM / 4);

  // ---- layer 0 weights/bias (K=256) ----
  hipLaunchKernelGGL(split_kernel, dim3(128), dim3(256), 0, stream, Uc0,
                     whi + 0 * HDIM * INDIM, wlo + 0 * HDIM * INDIM, HDIM * INDIM / 4);
  hipLaunchKernelGGL(split_kernel, dim3(128), dim3(256), 0, stream, Ua0,
                     whi + 1 * HDIM * INDIM, wlo + 1 * HDIM * INDIM, HDIM * INDIM / 4);
  hipLaunchKernelGGL(split_kernel, dim3(128), dim3(256), 0, stream, Uh0,
                     whi + 2 * HDIM * INDIM, wlo + 2 * HDIM * INDIM, HDIM * INDIM / 4);
  hipMemcpyAsync(bias + 0 * HDIM, bc0, HDIM * sizeof(float), hipMemcpyDeviceToDevice, stream);
  hipMemcpyAsync(bias + 1 * HDIM, ba0, HDIM * sizeof(float), hipMemcpyDeviceToDevice, stream);
  hipMemcpyAsync(bias + 2 * HDIM, bh0, HDIM * sizeof(float), hipMemcpyDeviceToDevice, stream);

  // ---- layer 0: chunked GEMM + scan ----
  for (int tc = 0; tc < NCH; ++tc) {
    hipLaunchKernelGGL(gemm_split_kernel, gemm_grid, dim3(256), 0, stream,
                       xhi + (long)tc * CHROWS * INDIM, xlo + (long)tc * CHROWS * INDIM,
                       whi, wlo, bias, p32, INDIM);
    hipLaunchKernelGGL(scan_kernel, dim3(BHDIM / 256), dim3(256), 0, stream,
                       p32, h0, hst, (tc == 0) ? 1 : 0, wc0, wa0,
                       y0hi + (long)tc * TCHUNK * BHDIM, y0lo + (long)tc * TCHUNK * BHDIM,
                       (float*)nullptr, (tc == NCH - 1) ? hn0 : (float*)nullptr);
  }

  // ---- layer 1 weights/bias (K=512) ----
  hipLaunchKernelGGL(split_kernel, dim3(256), dim3(256), 0, stream, Uc1,
                     whi + 0 * HDIM * HDIM, wlo + 0 * HDIM * HDIM, HDIM * HDIM / 4);
  hipLaunchKernelGGL(split_kernel, dim3(256), dim3(256), 0, stream, Ua1,
                     whi + 1 * HDIM * HDIM, wlo + 1 * HDIM * HDIM, HDIM * HDIM / 4);
  hipLaunchKernelGGL(split_kernel, dim3(256), dim3(256), 0, stream, Uh1,
                     whi + 2 * HDIM * HDIM, wlo + 2 * HDIM * HDIM, HDIM * HDIM / 4);
  hipMemcpyAsync(bias + 0 * HDIM, bc1, HDIM * sizeof(float), hipMemcpyDeviceToDevice, stream);
  hipMemcpyAsync(bias + 1 * HDIM, ba1, HDIM * sizeof(float), hipMemcpyDeviceToDevice, stream);
  hipMemcpyAsync(bias + 2 * HDIM, bh1, HDIM * sizeof(float), hipMemcpyDeviceToDevice, stream);

  // ---- layer 1: chunked GEMM + scan ----
  for (int tc = 0; tc < NCH; ++tc) {
    hipLaunchKernelGGL(gemm_split_kernel, gemm_grid, dim3(256), 0, stream,
                       y0hi + (long)tc * CHROWS * HDIM, y0lo + (long)tc * CHROWS * HDIM,
                       whi, wlo, bias, p32, HDIM);
    // NOTE r3/r4 bug fix: y1 must be offset per chunk (was overwriting t in [0,128)).
    hipLaunchKernelGGL(scan_kernel, dim3(BHDIM / 256), dim3(256), 0, stream,
                       p32, h0 + BHDIM, hst, (tc == 0) ? 1 : 0, wc1, wa1,
                       (f16*)nullptr, (f16*)nullptr, y1 + (long)tc * TCHUNK * BHDIM,
                       (tc == NCH - 1) ? hn1 : (float*)nullptr);
  }
}

// Round 6
// 2287.070 us; speedup vs baseline: 1.0321x; 1.0055x over previous
//
#include <hip/hip_runtime.h>
#include <cstdint>
#include <cstddef>

typedef _Float16 f16;
typedef _Float16 f16x4 __attribute__((ext_vector_type(4)));
typedef _Float16 f16x8 __attribute__((ext_vector_type(8)));
typedef float f32x4 __attribute__((ext_vector_type(4)));

#define AS1 __attribute__((address_space(1)))
#define AS3 __attribute__((address_space(3)))

// ---------- sizes ----------
#define SEQ 1024
#define BATCH 128
#define INDIM 256
#define HDIM 512
#define MROWS (SEQ * BATCH)          // 131072
#define NCOLS (3 * HDIM)             // 1536
#define BHDIM (BATCH * HDIM)         // 65536
#define TCHUNK 128
#define CHROWS (TCHUNK * BATCH)      // 16384

// workspace layout (bytes); total 506,730,496
#define P32_OFF   0ull                         // [16384][1536] f32 = 100,663,296
#define XHI_OFF   100663296ull                 // [131072][256] f16 = 67,108,864
#define XLO_OFF   167772160ull                 // [131072][256] f16 = 67,108,864
#define Y0HI_OFF  234881024ull                 // [131072][512] f16 = 134,217,728
#define Y0LO_OFF  369098752ull                 // [131072][512] f16 = 134,217,728
#define WHI_OFF   503316480ull                 // [1536][512] f16   = 1,572,864
#define WLO_OFF   504889344ull                 // [1536][512] f16   = 1,572,864
#define BIAS_OFF  506462208ull                 // [1536] f32
#define HST_OFF   506468352ull                 // [65536] f32
#define WS_NEEDED 506730496ull

__device__ __forceinline__ float fast_tanh(float x) {
  return 1.0f - 2.0f / (__expf(2.0f * x) + 1.0f);
}
__device__ __forceinline__ float fast_sigmoid(float x) {
  return 1.0f / (1.0f + __expf(-x));
}

__device__ __forceinline__ void gld16(const void* g, void* l) {
  __builtin_amdgcn_global_load_lds((const AS1 void*)g, (AS3 void*)l, 16, 0, 0);
}

// ---------- f32 -> (hi f16, lo' f16 = (v-hi)*2048) split ----------
__global__ __launch_bounds__(256) void split_kernel(const float* __restrict__ in,
                                                    f16* __restrict__ hi,
                                                    f16* __restrict__ lo, int n4) {
  int stride = gridDim.x * blockDim.x;
  for (int i = blockIdx.x * blockDim.x + threadIdx.x; i < n4; i += stride) {
    float4 v = reinterpret_cast<const float4*>(in)[i];
    f16x4 h4 = {(f16)v.x, (f16)v.y, (f16)v.z, (f16)v.w};
    f16x4 l4 = {(f16)((v.x - (float)h4[0]) * 2048.0f),
                (f16)((v.y - (float)h4[1]) * 2048.0f),
                (f16)((v.z - (float)h4[2]) * 2048.0f),
                (f16)((v.w - (float)h4[3]) * 2048.0f)};
    reinterpret_cast<f16x4*>(hi)[i] = h4;
    reinterpret_cast<f16x4*>(lo)[i] = l4;
  }
}

// ---------- GEMM: P[CHROWS,1536](f32) = (Ahi+Alo/2048).(Whi+Wlo/2048)^T + bias ----------
// Double-buffered prefetch (T3 minimum template): issue global_load_lds for tile k+1
// into buf^1 BEFORE ds_read+MFMA on buf; single __syncthreads per K-step (its implicit
// vmcnt(0) drain lands after the MFMA cover). Staging addressing identical to the
// r5-proven linear-LDS layout. 2x32KB LDS, 2 blocks/CU.
__global__ __launch_bounds__(256, 2) void gemm_split_kernel(
    const f16* __restrict__ Ahi, const f16* __restrict__ Alo,
    const f16* __restrict__ Whi, const f16* __restrict__ Wlo,
    const float* __restrict__ bias, float* __restrict__ P, int K) {
  constexpr int BK = 32;
  __shared__ f16 sAh[2][128 * BK];
  __shared__ f16 sAl[2][128 * BK];
  __shared__ f16 sBh[2][128 * BK];
  __shared__ f16 sBl[2][128 * BK];

  const int tid = threadIdx.x;
  const int lane = tid & 63;
  const int w = tid >> 6;
  const int wm = (w >> 1) * 64;
  const int wn = (w & 1) * 64;

  // XCD-aware bijective swizzle (gridDim.x = 1536, %8 == 0), n-block fastest
  const int per = gridDim.x >> 3;
  const int logical = (blockIdx.x & 7) * per + (blockIdx.x >> 3);
  const int nb = logical % (NCOLS / 128);
  const int mb = logical / (NCOLS / 128);
  const long m0 = (long)mb * 128;
  const int n0 = nb * 128;

  const int fr = lane & 15;
  const int fk = (lane >> 4) * 8;

  // staging: wave w stages bytes [w*2048, w*2048+2048) of each 8KB tile in 2 rounds of
  // 1KB (64 lanes x 16B). LDS dest is wave-uniform base; HW adds lane*16. Global source
  // is per-lane: row = off>>6 (64B/row), colb = off&63 — matches LDS landing slot.
  const int off0 = w * 2048 + lane * 16;
  const int off1 = off0 + 1024;
  const int row0 = off0 >> 6, colb0 = off0 & 63;
  const int row1 = off1 >> 6, colb1 = off1 & 63;
  const long aoff0 = ((m0 + row0) * (long)K) * 2 + colb0;
  const long aoff1 = ((m0 + row1) * (long)K) * 2 + colb1;
  const long boff0 = ((n0 + row0) * (long)K) * 2 + colb0;
  const long boff1 = ((n0 + row1) * (long)K) * 2 + colb1;
  const int ldsw = w * 2048;

  f32x4 acc[4][4] = {};
  f32x4 accc[4][4] = {};

  const int NT = K / BK;

#define STAGE(c, k0)                                                        \
  do {                                                                      \
    const long kb = (long)(k0) * (BK * 2);                                  \
    char* bAh = (char*)&sAh[(c)][0] + ldsw;                                 \
    char* bAl = (char*)&sAl[(c)][0] + ldsw;                                 \
    char* bBh = (char*)&sBh[(c)][0] + ldsw;                                 \
    char* bBl = (char*)&sBl[(c)][0] + ldsw;                                 \
    gld16((const char*)Ahi + aoff0 + kb, bAh);                              \
    gld16((const char*)Ahi + aoff1 + kb, bAh + 1024);                       \
    gld16((const char*)Alo + aoff0 + kb, bAl);                              \
    gld16((const char*)Alo + aoff1 + kb, bAl + 1024);                       \
    gld16((const char*)Whi + boff0 + kb, bBh);                              \
    gld16((const char*)Whi + boff1 + kb, bBh + 1024);                       \
    gld16((const char*)Wlo + boff0 + kb, bBl);                              \
    gld16((const char*)Wlo + boff1 + kb, bBl + 1024);                       \
  } while (0)

  int cur = 0;
  STAGE(0, 0);
  __syncthreads();  // implicit vmcnt(0): tile 0 ready

  for (int t = 0; t < NT; ++t) {
    if (t + 1 < NT) STAGE(cur ^ 1, t + 1);  // prefetch issued BEFORE compute

    f16x8 ah[4], al[4], bh[4], bl[4];
#pragma unroll
    for (int i = 0; i < 4; ++i) {
      ah[i] = *reinterpret_cast<const f16x8*>(&sAh[cur][(wm + i * 16 + fr) * BK + fk]);
      al[i] = *reinterpret_cast<const f16x8*>(&sAl[cur][(wm + i * 16 + fr) * BK + fk]);
      bh[i] = *reinterpret_cast<const f16x8*>(&sBh[cur][(wn + i * 16 + fr) * BK + fk]);
      bl[i] = *reinterpret_cast<const f16x8*>(&sBl[cur][(wn + i * 16 + fr) * BK + fk]);
    }

    __builtin_amdgcn_s_setprio(1);
#pragma unroll
    for (int i = 0; i < 4; ++i)
#pragma unroll
      for (int j = 0; j < 4; ++j) {
        acc[i][j]  = __builtin_amdgcn_mfma_f32_16x16x32_f16(ah[i], bh[j], acc[i][j], 0, 0, 0);
        accc[i][j] = __builtin_amdgcn_mfma_f32_16x16x32_f16(ah[i], bl[j], accc[i][j], 0, 0, 0);
        accc[i][j] = __builtin_amdgcn_mfma_f32_16x16x32_f16(al[i], bh[j], accc[i][j], 0, 0, 0);
      }
    __builtin_amdgcn_s_setprio(0);

    if (t + 1 < NT) {
      __syncthreads();  // drains prefetch vmcnt AFTER the MFMA cover; buffers flip
      cur ^= 1;
    }
  }
#undef STAGE

  // epilogue: C/D layout col = lane&15, row = (lane>>4)*4 + reg
  const int crow = (lane >> 4) * 4;
  const int ccol = lane & 15;
#pragma unroll
  for (int j = 0; j < 4; ++j) {
    int gc = n0 + wn + j * 16 + ccol;
    float bv = bias[gc];
#pragma unroll
    for (int i = 0; i < 4; ++i) {
      long gr = m0 + wm + i * 16 + crow;
#pragma unroll
      for (int r = 0; r < 4; ++r) {
        P[(gr + r) * NCOLS + gc] = acc[i][j][r] + accc[i][j][r] * (1.0f / 2048.0f) + bv;
      }
    }
  }
}

// ---------- BRC scan over one t-chunk: one thread per (b,h) chain ----------
// ALL output pointers are pre-offset by the caller to this chunk's base.
__global__ __launch_bounds__(256) void scan_kernel(
    const float* __restrict__ P, const float* __restrict__ hinit,
    float* __restrict__ hstate, int first,
    const float* __restrict__ wc, const float* __restrict__ wa,
    f16* __restrict__ Yhi, f16* __restrict__ Ylo,   // layer-0 split outputs (or null)
    float* __restrict__ Yf,                          // layer-1 f32 output (or null)
    float* __restrict__ HN) {
  const int j = blockIdx.x * 256 + threadIdx.x;  // 0..65535
  const int hh = j & (HDIM - 1);
  float h = first ? hinit[j] : hstate[j];
  const float wcv = wc[hh];
  const float wav = wa[hh];
  const float* p = P + (long)(j >> 9) * NCOLS + hh;
  long yo = j;
#pragma unroll 4
  for (int t = 0; t < TCHUNK; ++t) {
    float pc = p[0];
    float pa = p[HDIM];
    float ph = p[2 * HDIM];
    float c = fast_sigmoid(fmaf(wcv, h, pc));
    float a = 1.0f + fast_tanh(fmaf(wav, h, pa));
    h = c * h + (1.0f - c) * fast_tanh(fmaf(a, h, ph));
    if (Yhi) {
      f16 hv = (f16)h;
      Yhi[yo] = hv;
      Ylo[yo] = (f16)((h - (float)hv) * 2048.0f);
    }
    if (Yf) Yf[yo] = h;
    yo += BHDIM;
    p += BATCH * NCOLS;
  }
  hstate[j] = h;
  if (HN) HN[j] = h;
}

extern "C" void kernel_launch(void* const* d_in, const int* in_sizes, int n_in,
                              void* d_out, int out_size, void* d_ws, size_t ws_size,
                              hipStream_t stream) {
  const float* x   = (const float*)d_in[0];
  const float* h0  = (const float*)d_in[1];
  const float* Uc0 = (const float*)d_in[2];
  const float* wc0 = (const float*)d_in[3];
  const float* bc0 = (const float*)d_in[4];
  const float* Ua0 = (const float*)d_in[5];
  const float* wa0 = (const float*)d_in[6];
  const float* ba0 = (const float*)d_in[7];
  const float* Uh0 = (const float*)d_in[8];
  const float* bh0 = (const float*)d_in[9];
  const float* Uc1 = (const float*)d_in[10];
  const float* wc1 = (const float*)d_in[11];
  const float* bc1 = (const float*)d_in[12];
  const float* Ua1 = (const float*)d_in[13];
  const float* wa1 = (const float*)d_in[14];
  const float* ba1 = (const float*)d_in[15];
  const float* Uh1 = (const float*)d_in[16];
  const float* bh1 = (const float*)d_in[17];

  if (ws_size < WS_NEEDED) return;

  char* ws = (char*)d_ws;
  float* p32  = (float*)(ws + P32_OFF);
  f16* xhi    = (f16*)(ws + XHI_OFF);
  f16* xlo    = (f16*)(ws + XLO_OFF);
  f16* y0hi   = (f16*)(ws + Y0HI_OFF);
  f16* y0lo   = (f16*)(ws + Y0LO_OFF);
  f16* whi    = (f16*)(ws + WHI_OFF);
  f16* wlo    = (f16*)(ws + WLO_OFF);
  float* bias = (float*)(ws + BIAS_OFF);
  float* hst  = (float*)(ws + HST_OFF);

  float* y1  = (float*)d_out;
  float* hn0 = y1 + (long)SEQ * BHDIM;
  float* hn1 = hn0 + BHDIM;

  const int NCH = SEQ / TCHUNK;  // 8
  const dim3 gemm_grid(CHROWS / 128 * (NCOLS / 128));  // 1536, %8==0

  // ---- pre-split x ----
  hipLaunchKernelGGL(split_kernel, dim3(2048), dim3(256), 0, stream, x, xhi, xlo,
                     MROWS * INDIM / 4);

  // ---- layer 0 weights/bias (K=256) ----
  hipLaunchKernelGGL(split_kernel, dim3(128), dim3(256), 0, stream, Uc0,
                     whi + 0 * HDIM * INDIM, wlo + 0 * HDIM * INDIM, HDIM * INDIM / 4);
  hipLaunchKernelGGL(split_kernel, dim3(128), dim3(256), 0, stream, Ua0,
                     whi + 1 * HDIM * INDIM, wlo + 1 * HDIM * INDIM, HDIM * INDIM / 4);
  hipLaunchKernelGGL(split_kernel, dim3(128), dim3(256), 0, stream, Uh0,
                     whi + 2 * HDIM * INDIM, wlo + 2 * HDIM * INDIM, HDIM * INDIM / 4);
  hipMemcpyAsync(bias + 0 * HDIM, bc0, HDIM * sizeof(float), hipMemcpyDeviceToDevice, stream);
  hipMemcpyAsync(bias + 1 * HDIM, ba0, HDIM * sizeof(float), hipMemcpyDeviceToDevice, stream);
  hipMemcpyAsync(bias + 2 * HDIM, bh0, HDIM * sizeof(float), hipMemcpyDeviceToDevice, stream);

  // ---- layer 0: chunked GEMM + scan ----
  for (int tc = 0; tc < NCH; ++tc) {
    hipLaunchKernelGGL(gemm_split_kernel, gemm_grid, dim3(256), 0, stream,
                       xhi + (long)tc * CHROWS * INDIM, xlo + (long)tc * CHROWS * INDIM,
                       whi, wlo, bias, p32, INDIM);
    hipLaunchKernelGGL(scan_kernel, dim3(BHDIM / 256), dim3(256), 0, stream,
                       p32, h0, hst, (tc == 0) ? 1 : 0, wc0, wa0,
                       y0hi + (long)tc * TCHUNK * BHDIM, y0lo + (long)tc * TCHUNK * BHDIM,
                       (float*)nullptr, (tc == NCH - 1) ? hn0 : (float*)nullptr);
  }

  // ---- layer 1 weights/bias (K=512) ----
  hipLaunchKernelGGL(split_kernel, dim3(256), dim3(256), 0, stream, Uc1,
                     whi + 0 * HDIM * HDIM, wlo + 0 * HDIM * HDIM, HDIM * HDIM / 4);
  hipLaunchKernelGGL(split_kernel, dim3(256), dim3(256), 0, stream, Ua1,
                     whi + 1 * HDIM * HDIM, wlo + 1 * HDIM * HDIM, HDIM * HDIM / 4);
  hipLaunchKernelGGL(split_kernel, dim3(256), dim3(256), 0, stream, Uh1,
                     whi + 2 * HDIM * HDIM, wlo + 2 * HDIM * HDIM, HDIM * HDIM / 4);
  hipMemcpyAsync(bias + 0 * HDIM, bc1, HDIM * sizeof(float), hipMemcpyDeviceToDevice, stream);
  hipMemcpyAsync(bias + 1 * HDIM, ba1, HDIM * sizeof(float), hipMemcpyDeviceToDevice, stream);
  hipMemcpyAsync(bias + 2 * HDIM, bh1, HDIM * sizeof(float), hipMemcpyDeviceToDevice, stream);

  // ---- layer 1: chunked GEMM + scan ----
  for (int tc = 0; tc < NCH; ++tc) {
    hipLaunchKernelGGL(gemm_split_kernel, gemm_grid, dim3(256), 0, stream,
                       y0hi + (long)tc * CHROWS * HDIM, y0lo + (long)tc * CHROWS * HDIM,
                       whi, wlo, bias, p32, HDIM);
    hipLaunchKernelGGL(scan_kernel, dim3(BHDIM / 256), dim3(256), 0, stream,
                       p32, h0 + BHDIM, hst, (tc == 0) ? 1 : 0, wc1, wa1,
                       (f16*)nullptr, (f16*)nullptr, y1 + (long)tc * TCHUNK * BHDIM,
                       (tc == NCH - 1) ? hn1 : (float*)nullptr);
  }
}